// Round 3
// baseline (232.925 us; speedup 1.0000x reference)
//
#include <hip/hip_runtime.h>

// ---------------------------------------------------------------------------
// SphericalExpansion: ci[i,s,n,lm] = sum_{e: idx_i[e]==i, z[idx_j[e]]==s}
//                       fc(d_e) * (sum_k g_k(d_e) W[l(lm),n,k]) * Y_lm(dir_e)
// N_EDGES=800000, N_ATOMS=20000, NMAX=8, LM=16, N_SPECIES=4
//
// R2 design (still no HW data — theory-driven):
//  - bucket edges by atom (cap 128, Poisson(40) tail ~1e-28) -> no scan
//  - k_main: 1 block/atom, 128 thr:
//      * whole-bucket meta prefetch into LDS (one parallel gather burst,
//        cosf once per edge) -> chunk loop has ZERO global loads
//      * per 8-edge chunk: stage1 (g*fc + branchless Ylm via c*A*B selects),
//        barrier, stage2 (RIln: thread owns one W-row for 2 edges), barrier,
//        stage3 (acc[s] += rin*ylm, species branch via readfirstlane)
//      * ggfc/ylm/rin double-buffered by chunk parity -> 2 barriers/chunk
//  - all LDS patterns broadcast / <=2-way (free on gfx950, m136)
// ---------------------------------------------------------------------------

#define NMAXC      8
#define LMC        16
#define NSPECC     4
#define RCUT       5.0f
#define RIN        4.5f      // RC - SMOOTH_WIDTH
#define PI_F       3.14159265358979323846f
#define BUCKET_CAP 128

// Ylm = C[lm] * A * B;  A: 0->1, 1->x, 2->y, 3->z, 4->xy
// B: 0->1, 1->z, 2->3z2-1, 3->x2-y2, 4->3x2-y2, 5->5z2-1, 6->5z2-3, 7->x2-3y2
__device__ const int   d_Asel[16] = {0,2,3,1,4,2,0,1,0,2,4,2,3,1,3,1};
__device__ const int   d_Bsel[16] = {0,0,0,0,0,1,2,1,3,4,1,5,6,5,3,7};
__device__ const float d_Clm[16]  = {
    0.28209479177387814f, 0.4886025119029199f, 0.4886025119029199f,
    0.4886025119029199f,  1.0925484305920792f, 1.0925484305920792f,
    0.31539156525252005f, 1.0925484305920792f, 0.5462742152960396f,
    0.5900435899266435f,  2.890611442640554f,  0.4570457994644658f,
    0.3731763325901154f,  0.4570457994644658f, 1.445305721320277f,
    0.5900435899266435f };

// ---------------- bucket scatter (fast path) -------------------------------
__global__ void k_bucket(const int* __restrict__ idx_i, int* __restrict__ cursors,
                         int* __restrict__ edge_ids, int n_edges) {
    int e = blockIdx.x * blockDim.x + threadIdx.x;
    if (e < n_edges) {
        int a = idx_i[e];
        int c = atomicAdd(&cursors[a], 1);
        if (c < BUCKET_CAP) edge_ids[a * BUCKET_CAP + c] = e;
    }
}

// ---------------- CSR fallback: count / scan / scatter ---------------------
__global__ void k_count(const int* __restrict__ idx_i, int* __restrict__ counts,
                        int n_edges) {
    int e = blockIdx.x * blockDim.x + threadIdx.x;
    if (e < n_edges) atomicAdd(&counts[idx_i[e]], 1);
}

__global__ __launch_bounds__(1024) void k_scan(const int* __restrict__ counts,
                                               int* __restrict__ offsets,
                                               int* __restrict__ cursors, int n) {
    __shared__ int wsum[16];
    __shared__ int carry_s;
    int t = threadIdx.x;
    int lane = t & 63, w = t >> 6;
    if (t == 0) carry_s = 0;
    __syncthreads();
    for (int base = 0; base < n; base += 1024) {
        int i = base + t;
        int v = (i < n) ? counts[i] : 0;
        int x = v;
        #pragma unroll
        for (int off = 1; off < 64; off <<= 1) {
            int y = __shfl_up(x, off);
            if (lane >= off) x += y;
        }
        if (lane == 63) wsum[w] = x;
        __syncthreads();
        if (w == 0) {
            int ws = (lane < 16) ? wsum[lane] : 0;
            #pragma unroll
            for (int off = 1; off < 16; off <<= 1) {
                int y = __shfl_up(ws, off);
                if (lane >= off) ws += y;
            }
            if (lane < 16) wsum[lane] = ws;
        }
        __syncthreads();
        int wbase = (w > 0) ? wsum[w - 1] : 0;
        int inc = wbase + x;
        int carry = carry_s;
        if (i < n) {
            int exc = carry + inc - v;
            offsets[i] = exc;
            cursors[i] = exc;
        }
        __syncthreads();
        if (t == 1023) carry_s = carry + inc;
        __syncthreads();
    }
}

__global__ void k_scatter(const int* __restrict__ idx_i, int* __restrict__ cursors,
                          int* __restrict__ edge_ids, int n_edges) {
    int e = blockIdx.x * blockDim.x + threadIdx.x;
    if (e < n_edges) {
        int pos = atomicAdd(&cursors[idx_i[e]], 1);
        edge_ids[pos] = e;
    }
}

// ---------------- math helpers ---------------------------------------------
__device__ __forceinline__ float cutoff_fn(float d) {
    float tt = (d - RIN) * 2.0f;
    tt = fminf(fmaxf(tt, 0.0f), 1.0f);
    float ramp = 0.5f * (cosf(PI_F * tt) + 1.0f);
    return (d < RCUT) ? ramp : 0.0f;
}

__device__ __forceinline__ float sph_harm_sw(int lm, float x, float y, float z) {
    float x2 = x * x, y2 = y * y, z2 = z * z;
    switch (lm) {
        case 0:  return 0.28209479177387814f;
        case 1:  return 0.4886025119029199f * y;
        case 2:  return 0.4886025119029199f * z;
        case 3:  return 0.4886025119029199f * x;
        case 4:  return 1.0925484305920792f * x * y;
        case 5:  return 1.0925484305920792f * y * z;
        case 6:  return 0.31539156525252005f * (3.0f * z2 - 1.0f);
        case 7:  return 1.0925484305920792f * x * z;
        case 8:  return 0.5462742152960396f * (x2 - y2);
        case 9:  return 0.5900435899266435f * y * (3.0f * x2 - y2);
        case 10: return 2.890611442640554f * x * y * z;
        case 11: return 0.4570457994644658f * y * (5.0f * z2 - 1.0f);
        case 12: return 0.3731763325901154f * z * (5.0f * z2 - 3.0f);
        case 13: return 0.4570457994644658f * x * (5.0f * z2 - 1.0f);
        case 14: return 1.445305721320277f * z * (x2 - y2);
        default: return 0.5900435899266435f * x * (x2 - 3.0f * y2);
    }
}

// ---------------- main per-atom kernel -------------------------------------
// offsets == nullptr -> bucket layout (start = atom*BUCKET_CAP, cnt clamped)
// offsets != nullptr -> CSR layout (exact counts; segment loop handles >128)
__global__ __launch_bounds__(128) void k_main(
        const float* __restrict__ distances, const float* __restrict__ dirs,
        const float* __restrict__ W, const float* __restrict__ centers,
        const int* __restrict__ zarr, const int* __restrict__ idx_j,
        const int* __restrict__ offsets, const int* __restrict__ counts,
        const int* __restrict__ edge_ids, float* __restrict__ out) {
    const int atom = blockIdx.x;
    const int t = threadIdx.x;
    const int lm = t & 15;                  // fixed lm for stages 1/Y/3
    const int n_out = t >> 4;
    const int l = (lm >= 9) ? 3 : (lm >= 4) ? 2 : (lm >= 1) ? 1 : 0;
    const int l8n = l * 8 + n_out;          // rin index for stage3

    // stage2: thread owns W row (t&31) for local edges (t>>5) and (t>>5)+4
    const int lnw = t & 31;
    const int eA = t >> 5;
    const float4* wp = reinterpret_cast<const float4*>(W + (lnw << 4));
    const float4 w0 = wp[0], w1 = wp[1], w2 = wp[2], w3 = wp[3];
    const float ck   = centers[lm];
    const float c_lm = d_Clm[lm];
    const int   asel = d_Asel[lm], bsel = d_Bsel[lm];

    __shared__ float md[BUCKET_CAP], mfc[BUCKET_CAP];
    __shared__ float mx[BUCKET_CAP], my[BUCKET_CAP], mz[BUCKET_CAP];
    __shared__ int   ms[BUCKET_CAP];
    __shared__ float ggfc[2][8][16];        // [parity][edge][k]
    __shared__ float ylm [2][8][16];        // [parity][edge][lm]
    __shared__ float rin [2][8][32];        // [parity][edge][l*8+n]

    int cnt = counts[atom];
    int start;
    if (offsets) { start = offsets[atom]; }
    else         { start = atom * BUCKET_CAP; if (cnt > BUCKET_CAP) cnt = BUCKET_CAP; }

    float acc0 = 0.f, acc1 = 0.f, acc2 = 0.f, acc3 = 0.f;

    for (int seg = 0; seg < cnt; seg += BUCKET_CAP) {
        int scnt = cnt - seg;
        if (scnt > BUCKET_CAP) scnt = BUCKET_CAP;

        // ---- whole-segment meta prefetch: one parallel gather burst ----
        if (t < scnt) {
            int e = edge_ids[start + seg + t];
            float d = distances[e];
            md[t]  = d;
            mfc[t] = cutoff_fn(d);
            const float* dp = dirs + 3 * e;
            mx[t] = dp[0]; my[t] = dp[1]; mz[t] = dp[2];
            ms[t] = zarr[idx_j[e]];
        } else {
            md[t] = 1e9f; mfc[t] = 0.f;     // -> g*fc == 0 exactly
            mx[t] = 0.f; my[t] = 0.f; mz[t] = 0.f; ms[t] = 0;
        }
        __syncthreads();

        int p = 0;
        for (int base = 0; base < scnt; base += 8, p ^= 1) {
            const int eloc = t >> 4;        // local edge 0..7
            const int e = base + eloc;
            // ---- stage 1: g_k*fc and branchless Ylm ----
            {
                float dd = md[e] - ck;
                ggfc[p][eloc][lm] = __expf(-2.0f * dd * dd) * mfc[e];
                float x = mx[e], y = my[e], z = mz[e];
                float x2 = x * x, y2 = y * y, z2 = z * z, xyv = x * y;
                float A = (asel == 0) ? 1.0f :
                          (asel == 1) ? x    :
                          (asel == 2) ? y    :
                          (asel == 3) ? z    : xyv;
                float B = (bsel == 0) ? 1.0f :
                          (bsel == 1) ? z    :
                          (bsel == 2) ? fmaf(3.0f, z2, -1.0f) :
                          (bsel == 3) ? (x2 - y2)             :
                          (bsel == 4) ? fmaf(3.0f, x2, -y2)   :
                          (bsel == 5) ? fmaf(5.0f, z2, -1.0f) :
                          (bsel == 6) ? fmaf(5.0f, z2, -3.0f) :
                                        fmaf(-3.0f, y2, x2);
                ylm[p][eloc][lm] = c_lm * A * B;
            }
            __syncthreads();
            // ---- stage 2: RIln for 2 edges with this thread's W row ----
            {
                const float4* ga = reinterpret_cast<const float4*>(&ggfc[p][eA][0]);
                const float4* gb = reinterpret_cast<const float4*>(&ggfc[p][eA + 4][0]);
                float4 a0 = ga[0], a1 = ga[1], a2 = ga[2], a3 = ga[3];
                float4 b0 = gb[0], b1 = gb[1], b2 = gb[2], b3 = gb[3];
                float ra = a0.x * w0.x;
                ra = fmaf(a0.y, w0.y, ra); ra = fmaf(a0.z, w0.z, ra); ra = fmaf(a0.w, w0.w, ra);
                ra = fmaf(a1.x, w1.x, ra); ra = fmaf(a1.y, w1.y, ra); ra = fmaf(a1.z, w1.z, ra); ra = fmaf(a1.w, w1.w, ra);
                ra = fmaf(a2.x, w2.x, ra); ra = fmaf(a2.y, w2.y, ra); ra = fmaf(a2.z, w2.z, ra); ra = fmaf(a2.w, w2.w, ra);
                ra = fmaf(a3.x, w3.x, ra); ra = fmaf(a3.y, w3.y, ra); ra = fmaf(a3.z, w3.z, ra); ra = fmaf(a3.w, w3.w, ra);
                float rb = b0.x * w0.x;
                rb = fmaf(b0.y, w0.y, rb); rb = fmaf(b0.z, w0.z, rb); rb = fmaf(b0.w, w0.w, rb);
                rb = fmaf(b1.x, w1.x, rb); rb = fmaf(b1.y, w1.y, rb); rb = fmaf(b1.z, w1.z, rb); rb = fmaf(b1.w, w1.w, rb);
                rb = fmaf(b2.x, w2.x, rb); rb = fmaf(b2.y, w2.y, rb); rb = fmaf(b2.z, w2.z, rb); rb = fmaf(b2.w, w2.w, rb);
                rb = fmaf(b3.x, w3.x, rb); rb = fmaf(b3.y, w3.y, rb); rb = fmaf(b3.z, w3.z, rb); rb = fmaf(b3.w, w3.w, rb);
                rin[p][eA][lnw]     = ra;
                rin[p][eA + 4][lnw] = rb;
            }
            __syncthreads();
            // ---- stage 3: accumulate (padded slots contribute exact 0) ----
            #pragma unroll
            for (int ee = 0; ee < 8; ++ee) {
                float v = rin[p][ee][l8n] * ylm[p][ee][lm];
                int s = __builtin_amdgcn_readfirstlane(ms[base + ee]); // uniform
                if (s == 0)      acc0 += v;
                else if (s == 1) acc1 += v;
                else if (s == 2) acc2 += v;
                else             acc3 += v;
            }
            // no barrier: next chunk writes the other parity's buffers
        }
        __syncthreads();   // meta arrays reused by next segment's prefetch
    }

    // ---- store: ci[atom, s, n, lm], 512B coalesced per species ----
    const int ob = atom * (NSPECC * NMAXC * LMC) + t;
    out[ob + 0]   = acc0;
    out[ob + 128] = acc1;
    out[ob + 256] = acc2;
    out[ob + 384] = acc3;
}

// ---------------- last-resort fallback: direct atomics ---------------------
__global__ __launch_bounds__(128) void k_atomic(
        const float* __restrict__ distances, const float* __restrict__ dirs,
        const float* __restrict__ W, const float* __restrict__ centers,
        const int* __restrict__ zarr, const int* __restrict__ idx_i,
        const int* __restrict__ idx_j, float* __restrict__ out, int n_edges) {
    const int t = threadIdx.x;
    const int n = t >> 4, lm = t & 15;
    const int base = blockIdx.x * 8;

    __shared__ float4 gbuf[8][4];
    __shared__ float  ylm[8][16];
    __shared__ float  md[8], mfc[8], mx[8], my[8], mz[8];
    __shared__ int    ms[8], mi[8];

    const int l = (lm >= 9) ? 3 : (lm >= 4) ? 2 : (lm >= 1) ? 1 : 0;
    const float4* wp = reinterpret_cast<const float4*>(W + ((l * NMAXC + n) << 4));
    const float4 w0 = wp[0], w1 = wp[1], w2 = wp[2], w3 = wp[3];
    const float ck = centers[lm];

    if (t < 8) {
        int e = base + t;
        if (e < n_edges) {
            float d = distances[e];
            md[t] = d; mfc[t] = cutoff_fn(d);
            mx[t] = dirs[3 * e + 0];
            my[t] = dirs[3 * e + 1];
            mz[t] = dirs[3 * e + 2];
            ms[t] = zarr[idx_j[e]];
            mi[t] = idx_i[e];
        } else {
            md[t] = 1e9f; mfc[t] = 0.f;
            mx[t] = 0.f; my[t] = 0.f; mz[t] = 0.f; ms[t] = 0; mi[t] = 0;
        }
    }
    __syncthreads();
    {
        int e = t >> 4;
        float dd = md[e] - ck;
        reinterpret_cast<float*>(&gbuf[e][0])[lm] = __expf(-2.0f * dd * dd) * mfc[e];
    }
    {
        int e2 = t & 7, lm2 = t >> 3;
        ylm[e2][lm2] = sph_harm_sw(lm2, mx[e2], my[e2], mz[e2]);
    }
    __syncthreads();
    #pragma unroll
    for (int e = 0; e < 8; ++e) {
        float4 a0 = gbuf[e][0], a1 = gbuf[e][1], a2 = gbuf[e][2], a3 = gbuf[e][3];
        float r;
        r = a0.x * w0.x;
        r = fmaf(a0.y, w0.y, r); r = fmaf(a0.z, w0.z, r); r = fmaf(a0.w, w0.w, r);
        r = fmaf(a1.x, w1.x, r); r = fmaf(a1.y, w1.y, r); r = fmaf(a1.z, w1.z, r); r = fmaf(a1.w, w1.w, r);
        r = fmaf(a2.x, w2.x, r); r = fmaf(a2.y, w2.y, r); r = fmaf(a2.z, w2.z, r); r = fmaf(a2.w, w2.w, r);
        r = fmaf(a3.x, w3.x, r); r = fmaf(a3.y, w3.y, r); r = fmaf(a3.z, w3.z, r); r = fmaf(a3.w, w3.w, r);
        float v = r * ylm[e][lm];
        int target = (mi[e] * NSPECC + ms[e]) * (NMAXC * LMC) + t;
        unsafeAtomicAdd(&out[target], v);
    }
}

// ---------------------------------------------------------------------------
extern "C" void kernel_launch(void* const* d_in, const int* in_sizes, int n_in,
                              void* d_out, int out_size, void* d_ws, size_t ws_size,
                              hipStream_t stream) {
    const float* distances = (const float*)d_in[0];
    const float* dirs      = (const float*)d_in[1];
    const float* W         = (const float*)d_in[2];
    const float* centers   = (const float*)d_in[3];
    const int*   zarr      = (const int*)d_in[4];
    const int*   idx_i     = (const int*)d_in[5];
    const int*   idx_j     = (const int*)d_in[6];
    float*       out       = (float*)d_out;

    const int n_edges = in_sizes[0];
    const int n_atoms = in_sizes[4];

    const size_t need_bucket = (size_t)n_atoms * (BUCKET_CAP + 1) * sizeof(int);
    const size_t need_csr    = (size_t)(3 * n_atoms + n_edges) * sizeof(int);

    if (ws_size >= need_bucket) {
        // fast path: fixed-capacity buckets, no scan
        int* cursors  = (int*)d_ws;
        int* edge_ids = cursors + n_atoms;
        hipMemsetAsync(cursors, 0, (size_t)n_atoms * sizeof(int), stream);
        k_bucket<<<(n_edges + 255) / 256, 256, 0, stream>>>(idx_i, cursors, edge_ids, n_edges);
        k_main<<<n_atoms, 128, 0, stream>>>(distances, dirs, W, centers, zarr, idx_j,
                                            nullptr, cursors, edge_ids, out);
    } else if (ws_size >= need_csr) {
        // CSR path: count -> scan -> scatter
        int* counts   = (int*)d_ws;
        int* offsets  = counts + n_atoms;
        int* cursors  = offsets + n_atoms;
        int* edge_ids = cursors + n_atoms;
        hipMemsetAsync(counts, 0, (size_t)n_atoms * sizeof(int), stream);
        k_count<<<(n_edges + 255) / 256, 256, 0, stream>>>(idx_i, counts, n_edges);
        k_scan<<<1, 1024, 0, stream>>>(counts, offsets, cursors, n_atoms);
        k_scatter<<<(n_edges + 255) / 256, 256, 0, stream>>>(idx_i, cursors, edge_ids, n_edges);
        k_main<<<n_atoms, 128, 0, stream>>>(distances, dirs, W, centers, zarr, idx_j,
                                            offsets, cursors, edge_ids, out);
    } else {
        // last resort: direct atomics into output
        hipMemsetAsync(out, 0, (size_t)out_size * sizeof(float), stream);
        k_atomic<<<(n_edges + 7) / 8, 128, 0, stream>>>(distances, dirs, W, centers,
                                                        zarr, idx_i, idx_j, out, n_edges);
    }
}

// Round 4
// 198.722 us; speedup vs baseline: 1.1721x; 1.1721x over previous
//
#include <hip/hip_runtime.h>

// ---------------------------------------------------------------------------
// SphericalExpansion: ci[i,s,n,lm] = sum_{e: idx_i[e]==i, z[idx_j[e]]==s}
//                       fc(d_e) * (sum_k g_k(d_e) W[l(lm),n,k]) * Y_lm(dir_e)
// N_EDGES=800000, N_ATOMS=20000, NMAX=8, LM=16, N_SPECIES=4
//
// R4 design (first round with HW counters):
//  R3 measured: k_bucket ~114us (cursor 64B-line ping-pong: 16 cursors/line,
//  800K same-line atomics cross-XCD), k_main 116us latency-bound (FETCH 121MB
//  from 3-deep random gather chain; VALUBusy 47%, occ 50%).
//  Fixes:
//   1) k_rec_bucket scatters a full 16B record (d[+species in 2 mantissa
//      LSBs], x, y, z) with ALL edge-array reads coalesced; z-gather hits
//      80KB L2-resident array. One scattered 16B store per edge.
//   2) cursors padded to 1 per 64B line -> no atomic line ping-pong.
//   3) k_main: wave-independent. Each wave processes 4 edges/iter and keeps
//      all 128 (n,lm) outputs in 8 acc regs/lane. All LDS deps intra-wave
//      (in-order DS pipe + wave_barrier) -> ZERO barriers in main loop; one
//      __syncthreads for the final cross-wave reduce. Bucket reads are
//      contiguous 64B broadcasts -> zero gathers.
// ---------------------------------------------------------------------------

#define NMAXC   8
#define LMC     16
#define NSPECC  4
#define RCUT    5.0f
#define RIN_    4.5f      // RC - SMOOTH_WIDTH
#define PI_F    3.14159265358979323846f
#define CAP     128       // bucket capacity (Poisson(40) tail ~1e-28)
#define CPAD    16        // cursor padding in ints (64B/line)

// Ylm = C[lm] * A * B;  A: 0->1, 1->x, 2->y, 3->z, 4->xy
// B: 0->1, 1->z, 2->3z2-1, 3->x2-y2, 4->3x2-y2, 5->5z2-1, 6->5z2-3, 7->x2-3y2
__device__ const int   d_Asel[16] = {0,2,3,1,4,2,0,1,0,2,4,2,3,1,3,1};
__device__ const int   d_Bsel[16] = {0,0,0,0,0,1,2,1,3,4,1,5,6,5,3,7};
__device__ const float d_Clm[16]  = {
    0.28209479177387814f, 0.4886025119029199f, 0.4886025119029199f,
    0.4886025119029199f,  1.0925484305920792f, 1.0925484305920792f,
    0.31539156525252005f, 1.0925484305920792f, 0.5462742152960396f,
    0.5900435899266435f,  2.890611442640554f,  0.4570457994644658f,
    0.3731763325901154f,  0.4570457994644658f, 1.445305721320277f,
    0.5900435899266435f };

// ---------------- record scatter, fixed-cap buckets (T1) -------------------
__global__ void k_rec_bucket(const float* __restrict__ dist,
                             const float* __restrict__ dirs,
                             const int* __restrict__ zarr,
                             const int* __restrict__ idx_i,
                             const int* __restrict__ idx_j,
                             int* __restrict__ cursors_p,
                             float4* __restrict__ recs, int n_edges) {
    int e = blockIdx.x * blockDim.x + threadIdx.x;
    if (e >= n_edges) return;
    // coalesced reads; z gather is L2-resident (80KB)
    float d = dist[e];
    float x = dirs[3 * e + 0], y = dirs[3 * e + 1], zz = dirs[3 * e + 2];
    int s = zarr[idx_j[e]] & 3;
    int a = idx_i[e];
    int c = atomicAdd(&cursors_p[a * CPAD], 1);   // padded: no line sharing
    if (c >= CAP) return;
    unsigned db = (__float_as_uint(d) & ~3u) | (unsigned)s;  // <=2^-22 rel perturb
    float4 r; r.x = __uint_as_float(db); r.y = x; r.z = y; r.w = zz;
    recs[(size_t)a * CAP + c] = r;
}

// ---------------- CSR-exact record path (T2) -------------------------------
__global__ void k_count_p(const int* __restrict__ idx_i, int* __restrict__ counts_p,
                          int n_edges) {
    int e = blockIdx.x * blockDim.x + threadIdx.x;
    if (e < n_edges) atomicAdd(&counts_p[idx_i[e] * CPAD], 1);
}

__global__ __launch_bounds__(1024) void k_scan_p(const int* __restrict__ counts_p,
                                                 int* __restrict__ offsets,
                                                 int* __restrict__ cursors_p, int n) {
    __shared__ int wsum[16];
    __shared__ int carry_s;
    int t = threadIdx.x;
    int lane = t & 63, w = t >> 6;
    if (t == 0) carry_s = 0;
    __syncthreads();
    for (int base = 0; base < n; base += 1024) {
        int i = base + t;
        int v = (i < n) ? counts_p[i * CPAD] : 0;
        int x = v;
        #pragma unroll
        for (int off = 1; off < 64; off <<= 1) {
            int y = __shfl_up(x, off);
            if (lane >= off) x += y;
        }
        if (lane == 63) wsum[w] = x;
        __syncthreads();
        if (w == 0) {
            int ws = (lane < 16) ? wsum[lane] : 0;
            #pragma unroll
            for (int off = 1; off < 16; off <<= 1) {
                int y = __shfl_up(ws, off);
                if (lane >= off) ws += y;
            }
            if (lane < 16) wsum[lane] = ws;
        }
        __syncthreads();
        int wbase = (w > 0) ? wsum[w - 1] : 0;
        int inc = wbase + x;
        int carry = carry_s;
        if (i < n) {
            int exc = carry + inc - v;
            offsets[i] = exc;
            cursors_p[i * CPAD] = exc;
        }
        __syncthreads();
        if (t == 1023) carry_s = carry + inc;
        __syncthreads();
    }
}

__global__ void k_rec_csr(const float* __restrict__ dist,
                          const float* __restrict__ dirs,
                          const int* __restrict__ zarr,
                          const int* __restrict__ idx_i,
                          const int* __restrict__ idx_j,
                          int* __restrict__ cursors_p,
                          float4* __restrict__ recs, int n_edges) {
    int e = blockIdx.x * blockDim.x + threadIdx.x;
    if (e >= n_edges) return;
    float d = dist[e];
    float x = dirs[3 * e + 0], y = dirs[3 * e + 1], zz = dirs[3 * e + 2];
    int s = zarr[idx_j[e]] & 3;
    int a = idx_i[e];
    int c = atomicAdd(&cursors_p[a * CPAD], 1);
    unsigned db = (__float_as_uint(d) & ~3u) | (unsigned)s;
    float4 r; r.x = __uint_as_float(db); r.y = x; r.z = y; r.w = zz;
    recs[c] = r;
}

// ---------------- main per-atom kernel (wave-independent) ------------------
// offsets == nullptr -> T1 buckets (start=atom*CAP, cnt clamped to CAP)
// offsets != nullptr -> T2 CSR (exact counts)
__global__ __launch_bounds__(128) void k_main(
        const float4* __restrict__ recs, const float* __restrict__ W,
        const float* __restrict__ centers, const int* __restrict__ cnts_p,
        const int* __restrict__ offsets, float* __restrict__ out) {
    const int atom = blockIdx.x;
    const int t = threadIdx.x;
    const int w = t >> 6, L = t & 63;
    const int lm = L & 15;                 // stage1/3 lm ; stage1 k = lm
    const int eL = L >> 4;                 // stage1 local edge 0..3 ; stage3 n0
    const int l  = (lm >= 9) ? 3 : (lm >= 4) ? 2 : (lm >= 1) ? 1 : 0;
    const int r0 = l * 8 + eL;             // rin index, n-slot 0 (n=eL); slot1 = r0+4
    const int row = L & 31, p = L >> 5;    // stage2: W row, edge pair {p, p+2}

    const float ck   = centers[lm];
    const float c_lm = d_Clm[lm];
    const int   asel = d_Asel[lm], bsel = d_Bsel[lm];

    const float4* wp = reinterpret_cast<const float4*>(W + (row << 4));
    const float4 w0 = wp[0], w1 = wp[1], w2 = wp[2], w3 = wp[3];

    __shared__ float ggfc[2][4][16];       // [wave][edge][k]
    __shared__ float ylmS[2][4][16];       // [wave][edge][lm]
    __shared__ float rinS[2][4][32];       // [wave][edge][l*8+n]
    __shared__ int   msS [2][4];           // [wave][edge] species
    __shared__ float red [2][8][64];       // final cross-wave reduce

    int cnt = cnts_p[atom * CPAD];
    size_t rbase;
    if (offsets) { rbase = (size_t)offsets[atom]; }
    else         { rbase = (size_t)atom * CAP; if (cnt > CAP) cnt = CAP; }

    float a00 = 0.f, a01 = 0.f, a10 = 0.f, a11 = 0.f;
    float a20 = 0.f, a21 = 0.f, a30 = 0.f, a31 = 0.f;

    // wave w handles slots [it*8 + w*4, it*8 + w*4 + 4): fully wave-local
    for (int base = w * 4; base < cnt; base += 8) {
        int slot = base + eL;
        bool valid = slot < cnt;
        int rs = valid ? slot : base;                 // in-range dummy
        float4 rec = recs[rbase + rs];                // 64B broadcast load
        unsigned db = __float_as_uint(rec.x);
        int spec = db & 3;
        float d = rec.x, x = rec.y, y = rec.z, zz = rec.w;
        // ---- stage 1: g_k*fc and Ylm (branchless) ----
        float tt = fminf(fmaxf((d - RIN_) * 2.0f, 0.0f), 1.0f);
        float fcv = 0.5f * (__cosf(PI_F * tt) + 1.0f);
        float dd = d - ck;
        float g = __expf(-2.0f * dd * dd) * fcv;
        g = valid ? g : 0.0f;
        float x2 = x * x, y2 = y * y, z2 = zz * zz;
        float A = (asel == 0) ? 1.0f :
                  (asel == 1) ? x    :
                  (asel == 2) ? y    :
                  (asel == 3) ? zz   : x * y;
        float B = (bsel == 0) ? 1.0f :
                  (bsel == 1) ? zz   :
                  (bsel == 2) ? fmaf(3.0f, z2, -1.0f) :
                  (bsel == 3) ? (x2 - y2)             :
                  (bsel == 4) ? fmaf(3.0f, x2, -y2)   :
                  (bsel == 5) ? fmaf(5.0f, z2, -1.0f) :
                  (bsel == 6) ? fmaf(5.0f, z2, -3.0f) :
                                fmaf(-3.0f, y2, x2);
        float yv = c_lm * A * B;
        yv = valid ? yv : 0.0f;
        ggfc[w][eL][lm] = g;
        ylmS[w][eL][lm] = yv;
        if (lm == 0) msS[w][eL] = spec;
        __builtin_amdgcn_wave_barrier();   // keep DS order; in-order DS pipe
        // ---- stage 2: RIln; lane owns W row for edges p and p+2 ----
        {
            const float4* ga = reinterpret_cast<const float4*>(&ggfc[w][p][0]);
            const float4* gb = reinterpret_cast<const float4*>(&ggfc[w][p + 2][0]);
            float4 A0 = ga[0], A1 = ga[1], A2 = ga[2], A3 = ga[3];
            float4 B0 = gb[0], B1 = gb[1], B2 = gb[2], B3 = gb[3];
            float ra = A0.x * w0.x;
            ra = fmaf(A0.y, w0.y, ra); ra = fmaf(A0.z, w0.z, ra); ra = fmaf(A0.w, w0.w, ra);
            ra = fmaf(A1.x, w1.x, ra); ra = fmaf(A1.y, w1.y, ra); ra = fmaf(A1.z, w1.z, ra); ra = fmaf(A1.w, w1.w, ra);
            ra = fmaf(A2.x, w2.x, ra); ra = fmaf(A2.y, w2.y, ra); ra = fmaf(A2.z, w2.z, ra); ra = fmaf(A2.w, w2.w, ra);
            ra = fmaf(A3.x, w3.x, ra); ra = fmaf(A3.y, w3.y, ra); ra = fmaf(A3.z, w3.z, ra); ra = fmaf(A3.w, w3.w, ra);
            float rb = B0.x * w0.x;
            rb = fmaf(B0.y, w0.y, rb); rb = fmaf(B0.z, w0.z, rb); rb = fmaf(B0.w, w0.w, rb);
            rb = fmaf(B1.x, w1.x, rb); rb = fmaf(B1.y, w1.y, rb); rb = fmaf(B1.z, w1.z, rb); rb = fmaf(B1.w, w1.w, rb);
            rb = fmaf(B2.x, w2.x, rb); rb = fmaf(B2.y, w2.y, rb); rb = fmaf(B2.z, w2.z, rb); rb = fmaf(B2.w, w2.w, rb);
            rb = fmaf(B3.x, w3.x, rb); rb = fmaf(B3.y, w3.y, rb); rb = fmaf(B3.z, w3.z, rb); rb = fmaf(B3.w, w3.w, rb);
            rinS[w][p][row]     = ra;
            rinS[w][p + 2][row] = rb;
        }
        __builtin_amdgcn_wave_barrier();
        // ---- stage 3: accumulate this wave's 4 edges ----
        #pragma unroll
        for (int e = 0; e < 4; ++e) {
            float ye = ylmS[w][e][lm];
            float ra = rinS[w][e][r0];
            float rb = rinS[w][e][r0 + 4];
            int s = __builtin_amdgcn_readfirstlane(msS[w][e]);  // wave-uniform
            float v0 = ra * ye, v1 = rb * ye;
            if (s == 0)      { a00 += v0; a01 += v1; }
            else if (s == 1) { a10 += v0; a11 += v1; }
            else if (s == 2) { a20 += v0; a21 += v1; }
            else             { a30 += v0; a31 += v1; }
        }
        __builtin_amdgcn_wave_barrier();
    }

    // ---- cross-wave reduce + coalesced store ----
    red[w][0][L] = a00; red[w][1][L] = a01;
    red[w][2][L] = a10; red[w][3][L] = a11;
    red[w][4][L] = a20; red[w][5][L] = a21;
    red[w][6][L] = a30; red[w][7][L] = a31;
    __syncthreads();
    const int h = t >> 6, Ls = t & 63;    // h: n<4 / n>=4 half
    float* ob = out + (size_t)atom * (NSPECC * NMAXC * LMC);
    #pragma unroll
    for (int s = 0; s < 4; ++s) {
        float v = red[0][s * 2 + h][Ls] + red[1][s * 2 + h][Ls];
        ob[s * 128 + t] = v;
    }
}

// ---------------- last-resort fallback: direct atomics ---------------------
__device__ __forceinline__ float cutoff_fn(float d) {
    float tt = (d - RIN_) * 2.0f;
    tt = fminf(fmaxf(tt, 0.0f), 1.0f);
    float ramp = 0.5f * (cosf(PI_F * tt) + 1.0f);
    return (d < RCUT) ? ramp : 0.0f;
}

__device__ __forceinline__ float sph_harm_sw(int lm, float x, float y, float z) {
    float x2 = x * x, y2 = y * y, z2 = z * z;
    switch (lm) {
        case 0:  return 0.28209479177387814f;
        case 1:  return 0.4886025119029199f * y;
        case 2:  return 0.4886025119029199f * z;
        case 3:  return 0.4886025119029199f * x;
        case 4:  return 1.0925484305920792f * x * y;
        case 5:  return 1.0925484305920792f * y * z;
        case 6:  return 0.31539156525252005f * (3.0f * z2 - 1.0f);
        case 7:  return 1.0925484305920792f * x * z;
        case 8:  return 0.5462742152960396f * (x2 - y2);
        case 9:  return 0.5900435899266435f * y * (3.0f * x2 - y2);
        case 10: return 2.890611442640554f * x * y * z;
        case 11: return 0.4570457994644658f * y * (5.0f * z2 - 1.0f);
        case 12: return 0.3731763325901154f * z * (5.0f * z2 - 3.0f);
        case 13: return 0.4570457994644658f * x * (5.0f * z2 - 1.0f);
        case 14: return 1.445305721320277f * z * (x2 - y2);
        default: return 0.5900435899266435f * x * (x2 - 3.0f * y2);
    }
}

__global__ __launch_bounds__(128) void k_atomic(
        const float* __restrict__ distances, const float* __restrict__ dirs,
        const float* __restrict__ W, const float* __restrict__ centers,
        const int* __restrict__ zarr, const int* __restrict__ idx_i,
        const int* __restrict__ idx_j, float* __restrict__ out, int n_edges) {
    const int t = threadIdx.x;
    const int n = t >> 4, lm = t & 15;
    const int base = blockIdx.x * 8;

    __shared__ float4 gbuf[8][4];
    __shared__ float  ylm[8][16];
    __shared__ float  md[8], mfc[8], mx[8], my[8], mz[8];
    __shared__ int    ms[8], mi[8];

    const int l = (lm >= 9) ? 3 : (lm >= 4) ? 2 : (lm >= 1) ? 1 : 0;
    const float4* wp = reinterpret_cast<const float4*>(W + ((l * NMAXC + n) << 4));
    const float4 w0 = wp[0], w1 = wp[1], w2 = wp[2], w3 = wp[3];
    const float ck = centers[lm];

    if (t < 8) {
        int e = base + t;
        if (e < n_edges) {
            float d = distances[e];
            md[t] = d; mfc[t] = cutoff_fn(d);
            mx[t] = dirs[3 * e + 0];
            my[t] = dirs[3 * e + 1];
            mz[t] = dirs[3 * e + 2];
            ms[t] = zarr[idx_j[e]];
            mi[t] = idx_i[e];
        } else {
            md[t] = 1e9f; mfc[t] = 0.f;
            mx[t] = 0.f; my[t] = 0.f; mz[t] = 0.f; ms[t] = 0; mi[t] = 0;
        }
    }
    __syncthreads();
    {
        int e = t >> 4;
        float dd = md[e] - ck;
        reinterpret_cast<float*>(&gbuf[e][0])[lm] = __expf(-2.0f * dd * dd) * mfc[e];
    }
    {
        int e2 = t & 7, lm2 = t >> 3;
        ylm[e2][lm2] = sph_harm_sw(lm2, mx[e2], my[e2], mz[e2]);
    }
    __syncthreads();
    #pragma unroll
    for (int e = 0; e < 8; ++e) {
        float4 a0 = gbuf[e][0], a1 = gbuf[e][1], a2 = gbuf[e][2], a3 = gbuf[e][3];
        float r;
        r = a0.x * w0.x;
        r = fmaf(a0.y, w0.y, r); r = fmaf(a0.z, w0.z, r); r = fmaf(a0.w, w0.w, r);
        r = fmaf(a1.x, w1.x, r); r = fmaf(a1.y, w1.y, r); r = fmaf(a1.z, w1.z, r); r = fmaf(a1.w, w1.w, r);
        r = fmaf(a2.x, w2.x, r); r = fmaf(a2.y, w2.y, r); r = fmaf(a2.z, w2.z, r); r = fmaf(a2.w, w2.w, r);
        r = fmaf(a3.x, w3.x, r); r = fmaf(a3.y, w3.y, r); r = fmaf(a3.z, w3.z, r); r = fmaf(a3.w, w3.w, r);
        float v = r * ylm[e][lm];
        int target = (mi[e] * NSPECC + ms[e]) * (NMAXC * LMC) + t;
        unsafeAtomicAdd(&out[target], v);
    }
}

// ---------------------------------------------------------------------------
extern "C" void kernel_launch(void* const* d_in, const int* in_sizes, int n_in,
                              void* d_out, int out_size, void* d_ws, size_t ws_size,
                              hipStream_t stream) {
    const float* distances = (const float*)d_in[0];
    const float* dirs      = (const float*)d_in[1];
    const float* W         = (const float*)d_in[2];
    const float* centers   = (const float*)d_in[3];
    const int*   zarr      = (const int*)d_in[4];
    const int*   idx_i     = (const int*)d_in[5];
    const int*   idx_j     = (const int*)d_in[6];
    float*       out       = (float*)d_out;

    const int n_edges = in_sizes[0];
    const int n_atoms = in_sizes[4];

    const size_t curs_b  = (size_t)n_atoms * CPAD * sizeof(int);       // 1.28MB
    const size_t need_t1 = curs_b + (size_t)n_atoms * CAP * sizeof(float4) + 64;
    const size_t need_t2 = 2 * curs_b + (size_t)n_atoms * sizeof(int)
                         + (size_t)n_edges * sizeof(float4) + 64;

    if (ws_size >= need_t1) {
        // T1: fixed-cap record buckets, padded cursors, no scan
        int*    cursors_p = (int*)d_ws;
        float4* recs      = (float4*)((char*)d_ws + curs_b);
        hipMemsetAsync(cursors_p, 0, curs_b, stream);
        k_rec_bucket<<<(n_edges + 255) / 256, 256, 0, stream>>>(
            distances, dirs, zarr, idx_i, idx_j, cursors_p, recs, n_edges);
        k_main<<<n_atoms, 128, 0, stream>>>(recs, W, centers, cursors_p,
                                            nullptr, out);
    } else if (ws_size >= need_t2) {
        // T2: CSR-exact records (count -> scan -> scatter)
        int*    counts_p  = (int*)d_ws;
        int*    cursors_p = (int*)((char*)d_ws + curs_b);
        int*    offsets   = (int*)((char*)d_ws + 2 * curs_b);
        float4* recs      = (float4*)((char*)d_ws + 2 * curs_b
                                      + (size_t)n_atoms * sizeof(int));
        hipMemsetAsync(counts_p, 0, curs_b, stream);
        k_count_p<<<(n_edges + 255) / 256, 256, 0, stream>>>(idx_i, counts_p, n_edges);
        k_scan_p<<<1, 1024, 0, stream>>>(counts_p, offsets, cursors_p, n_atoms);
        k_rec_csr<<<(n_edges + 255) / 256, 256, 0, stream>>>(
            distances, dirs, zarr, idx_i, idx_j, cursors_p, recs, n_edges);
        k_main<<<n_atoms, 128, 0, stream>>>(recs, W, centers, counts_p,
                                            offsets, out);
    } else {
        // last resort: direct atomics into output
        hipMemsetAsync(out, 0, (size_t)out_size * sizeof(float), stream);
        k_atomic<<<(n_edges + 7) / 8, 128, 0, stream>>>(distances, dirs, W, centers,
                                                        zarr, idx_i, idx_j, out, n_edges);
    }
}